// Round 1
// baseline (1492.586 us; speedup 1.0000x reference)
//
#include <hip/hip_runtime.h>

namespace {

constexpr int BATCH = 8;
constexpr int SLEN  = 262144;
constexpr int TT    = 1023;   // (262144-512)/256 + 1
constexpr int NF    = 257;    // rfft bins
constexpr int FP2   = NF + 2; // padded freq row (zero pads at [0] and [258])
constexpr int NCH   = 24;     // channels stored in H (l3 output + head fused, never stored)
constexpr float EPS = 1e-5f;

// ---------------------------------------------------------------------------
// Kernel A: STFT (hann, 512-pt rfft via folded direct DFT) + l0 TD block.
// One workgroup per (b,t). Output: H[bt][c][f] for c in 0..7.
// ---------------------------------------------------------------------------
__global__ __launch_bounds__(256) void stft_l0_kernel(
    const float* __restrict__ x,
    const float* __restrict__ W1g, const float* __restrict__ b1g,
    const float* __restrict__ W2g, const float* __restrict__ b2g,
    float* __restrict__ H)
{
  __shared__ float2 cs[512];     // {cos, sin}(2*pi*n/512)
  __shared__ float  xw[512];     // windowed frame
  __shared__ float2 ab[256];     // {xw[n]+xw[512-n], xw[n]-xw[512-n]}, n=1..255
  __shared__ float  sre[FP2];
  __shared__ float  sim[FP2];
  __shared__ float  h1[4][FP2];
  __shared__ float  wW1[24], wb1[4], wW2[96], wb2[8];

  const int tid = threadIdx.x;
  const int bt  = blockIdx.x;
  const int b   = bt / TT;
  const int t   = bt - b * TT;
  const float* xp = x + (size_t)b * SLEN + (size_t)t * 256;

  if (tid < 24) wW1[tid] = W1g[tid];
  if (tid < 4)  wb1[tid] = b1g[tid];
  if (tid < 96) wW2[tid] = W2g[tid];
  if (tid < 8)  wb2[tid] = b2g[tid];

  const float STEP = 6.283185307179586f / 512.0f;
  for (int n = tid; n < 512; n += 256) {
    float sv, cv;
    sincosf(STEP * (float)n, &sv, &cv);
    cs[n] = make_float2(cv, sv);
    xw[n] = xp[n] * (0.5f - 0.5f * cv);   // hann window
  }
  __syncthreads();

  if (tid >= 1) {  // n = 1..255
    float u = xw[tid], v = xw[512 - tid];
    ab[tid] = make_float2(u + v, u - v);
  }
  __syncthreads();

  const float x0 = xw[0], x256 = xw[256];
  for (int k = tid; k < NF; k += 256) {
    float re = x0 + ((k & 1) ? -x256 : x256);
    float im = 0.f;
    int idx = k;  // (k*n) & 511, starting at n=1
    #pragma unroll 4
    for (int n = 1; n < 256; ++n) {
      float2 w = cs[idx];
      float2 p = ab[n];
      re = fmaf(p.x, w.x, re);
      im = fmaf(-p.y, w.y, im);
      idx = (idx + k) & 511;
    }
    sre[1 + k] = re;
    sim[1 + k] = im;
  }
  if (tid == 0) { sre[0] = 0.f; sim[0] = 0.f; sre[FP2-1] = 0.f; sim[FP2-1] = 0.f; }
  __syncthreads();

  // conv1: (f,2) -> (f,4), k=3 same, relu
  for (int f = tid; f < NF; f += 256) {
    float acc[4] = {wb1[0], wb1[1], wb1[2], wb1[3]};
    #pragma unroll
    for (int i = 0; i < 3; ++i) {
      float vr = sre[f + i], vi = sim[f + i];
      #pragma unroll
      for (int c = 0; c < 4; ++c)
        acc[c] = fmaf(vr, wW1[(i*2+0)*4 + c], fmaf(vi, wW1[(i*2+1)*4 + c], acc[c]));
    }
    #pragma unroll
    for (int c = 0; c < 4; ++c) h1[c][f + 1] = fmaxf(acc[c], 0.f);
  }
  if (tid < 4) { h1[tid][0] = 0.f; h1[tid][FP2-1] = 0.f; }
  __syncthreads();

  // conv2: (f,4) -> (f,8), k=3 same, outer relu, store channel-major
  const size_t obase = (size_t)bt * NCH * NF;
  for (int f = tid; f < NF; f += 256) {
    float acc[8];
    #pragma unroll
    for (int c = 0; c < 8; ++c) acc[c] = wb2[c];
    #pragma unroll
    for (int i = 0; i < 3; ++i)
      #pragma unroll
      for (int c4 = 0; c4 < 4; ++c4) {
        float hv = h1[c4][f + i];
        #pragma unroll
        for (int c = 0; c < 8; ++c)
          acc[c] = fmaf(hv, wW2[(i*4+c4)*8 + c], acc[c]);
      }
    #pragma unroll
    for (int c = 0; c < 8; ++c)
      H[obase + (size_t)c * NF + f] = fmaxf(acc[c], 0.f);
  }
}

// ---------------------------------------------------------------------------
// Transpose LN/depthwise tables to channel-major for coalesced reads.
// dst layout: [0,NEL) gT, [NEL,2NEL) bnT, [2NEL,5NEL) dwT[dt][c][f]
// ---------------------------------------------------------------------------
template<int CIN>
__global__ __launch_bounds__(256) void transpose_tbl(
    const float* __restrict__ g, const float* __restrict__ bn,
    const float* __restrict__ dw, float* __restrict__ dst)
{
  constexpr int NEL = CIN * NF;
  int idx = blockIdx.x * 256 + threadIdx.x;
  if (idx < NEL) {
    int c = idx / NF, f = idx - c * NF;
    dst[idx] = g[f * CIN + c];
  } else if (idx < 2 * NEL) {
    int r = idx - NEL;
    int c = r / NF, f = r - c * NF;
    dst[idx] = bn[f * CIN + c];
  } else if (idx < 5 * NEL) {
    int r = idx - 2 * NEL;
    int dt = r / NEL, r2 = r - dt * NEL;
    int c = r2 / NF, f = r2 - c * NF;
    dst[idx] = dw[(f * CIN + c) * 3 + dt];
  }
}

// ---------------------------------------------------------------------------
// Layer: LN over (F,C) at t,t-1,t-2 + causal depthwise(time,K=3) + TD block.
// One workgroup per (b,t). HEAD=true fuses fc1/fc2/sigmoid (layer 3).
// ---------------------------------------------------------------------------
template<int CIN, bool HEAD>
__global__ __launch_bounds__(256) void layer_kernel(
    const float* __restrict__ H, float* __restrict__ Hout,
    const float* __restrict__ tbl,
    const float* __restrict__ W1g, const float* __restrict__ b1g,
    const float* __restrict__ W2g, const float* __restrict__ b2g,
    const float* __restrict__ fc1W, const float* __restrict__ fc1b,
    const float* __restrict__ fc2W, const float* __restrict__ fc2b,
    float* __restrict__ out)
{
  constexpr int NEL  = CIN * NF;
  constexpr int NPER = (NEL + 255) / 256;

  __shared__ float y[CIN * FP2];       // depthwise output, zero-padded rows
  __shared__ float h1s[8 * FP2];       // conv1 output, zero-padded rows
  __shared__ float wW1[3 * CIN * 8], wb1[8], wW2[192], wb2[8];
  __shared__ float red[8];
  __shared__ float xstash[HEAD ? NEL : 1];     // raw input at time t (for head)
  __shared__ float out2[HEAD ? 8 * NF : 1];    // this layer's 8 outputs (for head)
  __shared__ float wfc1[HEAD ? 96 : 1];

  const int tid = threadIdx.x;
  const int bt  = blockIdx.x;
  const int b   = bt / TT;
  const int t   = bt - b * TT;

  const float* gT  = tbl;
  const float* bnT = tbl + NEL;
  const float* dwT = tbl + 2 * NEL;

  for (int i = tid; i < CIN * FP2; i += 256) y[i] = 0.f;
  for (int i = tid; i < 8 * FP2;  i += 256) h1s[i] = 0.f;
  for (int i = tid; i < 3 * CIN * 8; i += 256) wW1[i] = W1g[i];
  if (tid < 192) wW2[tid] = W2g[tid];
  if (tid < 8) { wb1[tid] = b1g[tid]; wb2[tid] = b2g[tid]; }
  if constexpr (HEAD) { if (tid < 96) wfc1[tid] = fc1W[tid]; }
  __syncthreads();

  for (int dt = 0; dt < 3; ++dt) {
    const int tt = t - 2 + dt;
    if (tt < 0) continue;  // uniform across block: zero contribution (causal pad)
    const float* xg = H + (size_t)(b * TT + tt) * NCH * NF;

    float xv[NPER];
    float s1 = 0.f, s2 = 0.f;
    #pragma unroll
    for (int j = 0; j < NPER; ++j) {
      int idx = tid + j * 256;
      float v = (idx < NEL) ? xg[idx] : 0.f;
      xv[j] = v;
      s1 += v;
      s2 = fmaf(v, v, s2);
    }
    if constexpr (HEAD) {
      if (dt == 2) {
        #pragma unroll
        for (int j = 0; j < NPER; ++j) {
          int idx = tid + j * 256;
          if (idx < NEL) xstash[idx] = xv[j];
        }
      }
    }
    #pragma unroll
    for (int off = 32; off > 0; off >>= 1) {
      s1 += __shfl_down(s1, off, 64);
      s2 += __shfl_down(s2, off, 64);
    }
    const int wave = tid >> 6;
    if ((tid & 63) == 0) { red[wave * 2] = s1; red[wave * 2 + 1] = s2; }
    __syncthreads();
    const float tot1 = red[0] + red[2] + red[4] + red[6];
    const float tot2 = red[1] + red[3] + red[5] + red[7];
    const float mu   = tot1 * (1.0f / NEL);
    const float var  = tot2 * (1.0f / NEL) - mu * mu;
    const float rstd = rsqrtf(var + EPS);

    #pragma unroll
    for (int j = 0; j < NPER; ++j) {
      int idx = tid + j * 256;
      if (idx < NEL) {
        int c = idx / NF;
        int f = idx - c * NF;
        float xn = fmaf((xv[j] - mu) * rstd, gT[idx], bnT[idx]);
        float* yp = &y[c * FP2 + 1 + f];
        *yp = fmaf(xn, dwT[dt * NEL + idx], *yp);
      }
    }
    __syncthreads();  // protects red (next dt) and finalizes y (last dt)
  }

  // conv1: (f,CIN) -> (f,8), k=3 same, relu
  for (int f = tid; f < NF; f += 256) {
    float acc[8];
    #pragma unroll
    for (int c = 0; c < 8; ++c) acc[c] = wb1[c];
    #pragma unroll
    for (int i = 0; i < 3; ++i)
      for (int cin = 0; cin < CIN; ++cin) {
        float yv = y[cin * FP2 + f + i];
        #pragma unroll
        for (int c = 0; c < 8; ++c)
          acc[c] = fmaf(yv, wW1[(i * CIN + cin) * 8 + c], acc[c]);
      }
    #pragma unroll
    for (int c = 0; c < 8; ++c) h1s[c * FP2 + f + 1] = fmaxf(acc[c], 0.f);
  }
  __syncthreads();

  // conv2: (f,8) -> (f,8), k=3 same, outer relu
  for (int f = tid; f < NF; f += 256) {
    float acc[8];
    #pragma unroll
    for (int c = 0; c < 8; ++c) acc[c] = wb2[c];
    #pragma unroll
    for (int i = 0; i < 3; ++i)
      #pragma unroll
      for (int c8 = 0; c8 < 8; ++c8) {
        float hv = h1s[c8 * FP2 + f + i];
        #pragma unroll
        for (int c = 0; c < 8; ++c)
          acc[c] = fmaf(hv, wW2[(i * 8 + c8) * 8 + c], acc[c]);
      }
    if constexpr (!HEAD) {
      const size_t obase = (size_t)bt * NCH * NF + (size_t)CIN * NF;
      #pragma unroll
      for (int c = 0; c < 8; ++c)
        Hout[obase + (size_t)c * NF + f] = fmaxf(acc[c], 0.f);
    } else {
      #pragma unroll
      for (int c = 0; c < 8; ++c)
        out2[c * NF + f] = fmaxf(acc[c], 0.f);
    }
  }

  if constexpr (HEAD) {
    __syncthreads();
    float partial = 0.f;
    if (tid < NF - 2) {
      float acc = fc1b[0];
      #pragma unroll
      for (int i = 0; i < 3; ++i) {
        for (int c = 0; c < 24; ++c)
          acc = fmaf(xstash[c * NF + tid + i], wfc1[i * 32 + c], acc);
        #pragma unroll
        for (int c = 0; c < 8; ++c)
          acc = fmaf(out2[c * NF + tid + i], wfc1[i * 32 + 24 + c], acc);
      }
      acc = fmaxf(acc, 0.f);
      partial = acc * fc2W[tid];
    }
    #pragma unroll
    for (int off = 32; off > 0; off >>= 1) partial += __shfl_down(partial, off, 64);
    const int wave = tid >> 6;
    if ((tid & 63) == 0) red[wave] = partial;
    __syncthreads();
    if (tid == 0) {
      float tot = red[0] + red[1] + red[2] + red[3] + fc2b[0];
      out[bt] = 1.0f / (1.0f + expf(-tot));
    }
  }
}

}  // namespace

extern "C" void kernel_launch(void* const* d_in, const int* in_sizes, int n_in,
                              void* d_out, int out_size, void* d_ws, size_t ws_size,
                              hipStream_t stream) {
  const float* x     = (const float*)d_in[0];
  const float* l0W1  = (const float*)d_in[1];
  const float* l0b1  = (const float*)d_in[2];
  const float* l0W2  = (const float*)d_in[3];
  const float* l0b2  = (const float*)d_in[4];
  float* out = (float*)d_out;
  float* ws  = (float*)d_ws;

  // Workspace layout (floats): H [nbt*24*257], then transposed tables.
  const int nbt = BATCH * TT;                       // 8184
  const size_t Hsz = (size_t)nbt * NCH * NF;        // 50,478,912 floats
  float* H    = ws;
  float* tbl1 = ws + Hsz;                           // 5*2056
  float* tbl2 = tbl1 + 5 * (8 * NF);
  float* tbl3 = tbl2 + 5 * (16 * NF);

  dim3 blk(256);

  transpose_tbl<8><<<dim3((5 * 8 * NF + 255) / 256), blk, 0, stream>>>(
      (const float*)d_in[5], (const float*)d_in[6], (const float*)d_in[7], tbl1);
  transpose_tbl<16><<<dim3((5 * 16 * NF + 255) / 256), blk, 0, stream>>>(
      (const float*)d_in[12], (const float*)d_in[13], (const float*)d_in[14], tbl2);
  transpose_tbl<24><<<dim3((5 * 24 * NF + 255) / 256), blk, 0, stream>>>(
      (const float*)d_in[19], (const float*)d_in[20], (const float*)d_in[21], tbl3);

  stft_l0_kernel<<<dim3(nbt), blk, 0, stream>>>(x, l0W1, l0b1, l0W2, l0b2, H);

  layer_kernel<8, false><<<dim3(nbt), blk, 0, stream>>>(
      H, H, tbl1,
      (const float*)d_in[8], (const float*)d_in[9],
      (const float*)d_in[10], (const float*)d_in[11],
      nullptr, nullptr, nullptr, nullptr, nullptr);

  layer_kernel<16, false><<<dim3(nbt), blk, 0, stream>>>(
      H, H, tbl2,
      (const float*)d_in[15], (const float*)d_in[16],
      (const float*)d_in[17], (const float*)d_in[18],
      nullptr, nullptr, nullptr, nullptr, nullptr);

  layer_kernel<24, true><<<dim3(nbt), blk, 0, stream>>>(
      H, nullptr, tbl3,
      (const float*)d_in[22], (const float*)d_in[23],
      (const float*)d_in[24], (const float*)d_in[25],
      (const float*)d_in[26], (const float*)d_in[27],
      (const float*)d_in[28], (const float*)d_in[29],
      out);
}